// Round 1
// baseline (141.947 us; speedup 1.0000x reference)
//
#include <hip/hip_runtime.h>

// Correction_Module_dense_checksum: ABFT 2x2 block checksum verify + correct.
// A: (8192, 64) f32, B: (8192, 64) f32, C_faulty: (8192, 8192) f32 -> out f32.
// check[i][j] = (B[2i]+B[2i+1]) . (A[2j]+A[2j+1]); actual = 2x2 block sum of C.
// Flag iff |actual - check| > ATOL + RTOL*|check|; flagged 2x2 blocks are
// recomputed as B[r] . A[c]. Fault margin is ~100 vs tol ~1e-3 -> mask is
// reproduction-robust under any f32 summation order.

constexpr int   Ddim = 64;
constexpr int   NCOL = 8192;
constexpr float ATOL = 1e-3f;
constexpr float RTOL = 1e-4f;

__device__ __forceinline__ void recompute2x2(const float* __restrict__ A,
                                             const float* __restrict__ B,
                                             int r0, int c0,
                                             float& e00, float& e01,
                                             float& e10, float& e11)
{
    const float* b0 = B + (size_t)r0 * Ddim;
    const float* b1 = b0 + Ddim;
    const float* a0 = A + (size_t)c0 * Ddim;
    const float* a1 = a0 + Ddim;
    float d00 = 0.f, d01 = 0.f, d10 = 0.f, d11 = 0.f;
    for (int d = 0; d < Ddim; ++d) {
        float bb0 = b0[d], bb1 = b1[d], aa0 = a0[d], aa1 = a1[d];
        d00 += bb0 * aa0;
        d01 += bb0 * aa1;
        d10 += bb1 * aa0;
        d11 += bb1 * aa1;
    }
    e00 = d00; e01 = d01; e10 = d10; e11 = d11;
}

__global__ __launch_bounds__(256)
void correct_kernel(const float* __restrict__ A, const float* __restrict__ B,
                    const float* __restrict__ C, float* __restrict__ out)
{
    // [d][j] layout: inner-loop lane reads vary j -> spread across all 32
    // banks (conflict-free). [j][d] would be 16-way conflicted.
    __shared__ float ACs[64][64];   // checksum of A row-pairs, 16 KiB
    __shared__ float BCs[64][64];   // checksum of B row-pairs, 16 KiB

    const int t  = threadIdx.x;
    const int bx = blockIdx.x;      // 128-col tile
    const int by = blockIdx.y;      // 128-row tile
    const int tx = t & 15;
    const int ty = t >> 4;

    // ---- C patch loads (issued first: overlap staging + dot loop) ----
    // Thread covers C rows [8ty, 8ty+8), cols {4tx..4tx+3, 64+4tx..64+4tx+3}
    // within the tile. 16 lanes x 16B = dense 256B segments per instr.
    const size_t rowbase = (size_t)(by * 128 + 8 * ty) * NCOL
                         + (size_t)(bx * 128 + 4 * tx);
    float4 cv[8][2];
    #pragma unroll
    for (int rr = 0; rr < 8; ++rr) {
        const float* p = C + rowbase + (size_t)rr * NCOL;
        cv[rr][0] = *(const float4*)(p);
        cv[rr][1] = *(const float4*)(p + 64);
    }

    // ---- stage AC/BC (pair-sum on the fly; A,B are L2-resident) ----
    {
        const int j  = t & 63;      // block index within tile
        const int dq = t >> 6;      // d-quarter
        const float* arow = A + (size_t)(bx * 64 + j) * 2 * Ddim;
        const float* brow = B + (size_t)(by * 64 + j) * 2 * Ddim;
        #pragma unroll
        for (int l = 0; l < 4; ++l) {
            const int d0 = dq * 16 + l * 4;
            float4 a0 = *(const float4*)(arow + d0);
            float4 a1 = *(const float4*)(arow + Ddim + d0);
            float4 b0 = *(const float4*)(brow + d0);
            float4 b1 = *(const float4*)(brow + Ddim + d0);
            // lanes vary j -> banks j%32, 2 lanes/bank (free)
            ACs[d0 + 0][j] = a0.x + a1.x;
            ACs[d0 + 1][j] = a0.y + a1.y;
            ACs[d0 + 2][j] = a0.z + a1.z;
            ACs[d0 + 3][j] = a0.w + a1.w;
            BCs[d0 + 0][j] = b0.x + b1.x;
            BCs[d0 + 1][j] = b0.y + b1.y;
            BCs[d0 + 2][j] = b0.z + b1.z;
            BCs[d0 + 3][j] = b0.w + b1.w;
        }
    }
    __syncthreads();

    // ---- checksum dots: thread owns blocks bi in 4ty+{0..3},
    //      bj in {2tx, 2tx+1, 32+2tx, 33+2tx} ----
    float acc[4][4];
    #pragma unroll
    for (int a = 0; a < 4; ++a)
        #pragma unroll
        for (int b = 0; b < 4; ++b) acc[a][b] = 0.f;

    #pragma unroll 8
    for (int d = 0; d < 64; ++d) {
        float4 bc   = *(const float4*)&BCs[d][4 * ty];      // b128, bcast-free
        float2 ac01 = *(const float2*)&ACs[d][2 * tx];      // b64, conflict-free
        float2 ac23 = *(const float2*)&ACs[d][2 * tx + 32];
        const float bcv[4] = {bc.x, bc.y, bc.z, bc.w};
        const float acv[4] = {ac01.x, ac01.y, ac23.x, ac23.y};
        #pragma unroll
        for (int a = 0; a < 4; ++a)
            #pragma unroll
            for (int b = 0; b < 4; ++b)
                acc[a][b] += bcv[a] * acv[b];
    }

    // ---- block sums, compare, rare fix, store ----
    #pragma unroll
    for (int a = 0; a < 4; ++a) {
        float4 t0 = cv[2 * a][0], u0 = cv[2 * a + 1][0];
        float4 t1 = cv[2 * a][1], u1 = cv[2 * a + 1][1];
        float s0 = (t0.x + t0.y) + (u0.x + u0.y);
        float s1 = (t0.z + t0.w) + (u0.z + u0.w);
        float s2 = (t1.x + t1.y) + (u1.x + u1.y);
        float s3 = (t1.z + t1.w) + (u1.z + u1.w);
        bool f0 = fabsf(s0 - acc[a][0]) > ATOL + RTOL * fabsf(acc[a][0]);
        bool f1 = fabsf(s1 - acc[a][1]) > ATOL + RTOL * fabsf(acc[a][1]);
        bool f2 = fabsf(s2 - acc[a][2]) > ATOL + RTOL * fabsf(acc[a][2]);
        bool f3 = fabsf(s3 - acc[a][3]) > ATOL + RTOL * fabsf(acc[a][3]);
        if (f0 | f1 | f2 | f3) {   // ~670 of 16.7M blocks: fully divergent OK
            const int r0    = by * 128 + 8 * ty + 2 * a;
            const int cbase = bx * 128 + 4 * tx;
            if (f0) recompute2x2(A, B, r0, cbase,      t0.x, t0.y, u0.x, u0.y);
            if (f1) recompute2x2(A, B, r0, cbase + 2,  t0.z, t0.w, u0.z, u0.w);
            if (f2) recompute2x2(A, B, r0, cbase + 64, t1.x, t1.y, u1.x, u1.y);
            if (f3) recompute2x2(A, B, r0, cbase + 66, t1.z, t1.w, u1.z, u1.w);
        }
        float* q0 = out + rowbase + (size_t)(2 * a) * NCOL;
        float* q1 = out + rowbase + (size_t)(2 * a + 1) * NCOL;
        *(float4*)(q0)      = t0;
        *(float4*)(q0 + 64) = t1;
        *(float4*)(q1)      = u0;
        *(float4*)(q1 + 64) = u1;
    }
}

extern "C" void kernel_launch(void* const* d_in, const int* in_sizes, int n_in,
                              void* d_out, int out_size, void* d_ws, size_t ws_size,
                              hipStream_t stream) {
    const float* A = (const float*)d_in[0];   // (8192, 64)
    const float* B = (const float*)d_in[1];   // (8192, 64)
    const float* C = (const float*)d_in[2];   // (8192, 8192) faulty
    float* out = (float*)d_out;               // (8192, 8192)
    dim3 grid(NCOL / 128, NCOL / 128);        // 64 x 64 tiles
    correct_kernel<<<grid, 256, 0, stream>>>(A, B, C, out);
}

// Round 3
// 112.948 us; speedup vs baseline: 1.2567x; 1.2567x over previous
//
#include <hip/hip_runtime.h>

// Correction_Module_dense_checksum: ABFT 2x2 block checksum verify + correct.
// A: (8192, 64) f32, B: (8192, 64) f32, C_faulty: (8192, 8192) f32 -> out f32.
// check[i][j] = (B[2i]+B[2i+1]) . (A[2j]+A[2j+1]); actual = 2x2 block sum of C.
// Flag iff |actual - check| > ATOL + RTOL*|check|; flagged 2x2 blocks are
// recomputed as B[r] . A[c]. Fault margin is ~100 vs tol ~1e-3 -> mask is
// reproduction-robust under any f32 summation order.
//
// R2: raise memory-level parallelism. R1 had VGPR_Count=64 -> compiler
// serialized the 32 global loads (latency-bound: 2.6 TB/s, VALU 16%, occ 35%).
// launch_bounds(256,4) caps at 128 VGPR (occupancy is LDS-bound at 5 blk/CU
// anyway); staging loads issued before cv loads so the LDS-write waitcnt
// leaves cv in flight; nontemporal stores keep L3 for C.
// R3: nontemporal builtin needs a native vector type, not HIP_vector_type.

constexpr int   Ddim = 64;
constexpr int   NCOL = 8192;
constexpr float ATOL = 1e-3f;
constexpr float RTOL = 1e-4f;

typedef float vfloat4 __attribute__((ext_vector_type(4)));

__device__ __forceinline__ void nt_store4(float* p, float4 v) {
    vfloat4 w = {v.x, v.y, v.z, v.w};
    __builtin_nontemporal_store(w, (vfloat4*)p);
}

__device__ __forceinline__ void recompute2x2(const float* __restrict__ A,
                                             const float* __restrict__ B,
                                             int r0, int c0,
                                             float& e00, float& e01,
                                             float& e10, float& e11)
{
    const float* b0 = B + (size_t)r0 * Ddim;
    const float* b1 = b0 + Ddim;
    const float* a0 = A + (size_t)c0 * Ddim;
    const float* a1 = a0 + Ddim;
    float d00 = 0.f, d01 = 0.f, d10 = 0.f, d11 = 0.f;
    for (int d = 0; d < Ddim; ++d) {
        float bb0 = b0[d], bb1 = b1[d], aa0 = a0[d], aa1 = a1[d];
        d00 += bb0 * aa0;
        d01 += bb0 * aa1;
        d10 += bb1 * aa0;
        d11 += bb1 * aa1;
    }
    e00 = d00; e01 = d01; e10 = d10; e11 = d11;
}

__global__ __launch_bounds__(256, 4)
void correct_kernel(const float* __restrict__ A, const float* __restrict__ B,
                    const float* __restrict__ C, float* __restrict__ out)
{
    // [d][j] layout: inner-loop lane reads vary j -> spread across all 32
    // banks (conflict-free). [j][d] would be 16-way conflicted.
    __shared__ float ACs[64][64];   // checksum of A row-pairs, 16 KiB
    __shared__ float BCs[64][64];   // checksum of B row-pairs, 16 KiB

    const int t  = threadIdx.x;
    const int bx = blockIdx.x;      // 128-col tile
    const int by = blockIdx.y;      // 128-row tile
    const int tx = t & 15;
    const int ty = t >> 4;

    // ---- staging loads FIRST (they gate the barrier). 16 float4 live. ----
    const int j  = t & 63;          // block index within tile
    const int dq = t >> 6;          // d-quarter
    const float* arow = A + (size_t)(bx * 64 + j) * 2 * Ddim;
    const float* brow = B + (size_t)(by * 64 + j) * 2 * Ddim;
    float4 sa0[4], sa1[4], sb0[4], sb1[4];
    #pragma unroll
    for (int l = 0; l < 4; ++l) {
        const int d0 = dq * 16 + l * 4;
        sa0[l] = *(const float4*)(arow + d0);
        sa1[l] = *(const float4*)(arow + Ddim + d0);
        sb0[l] = *(const float4*)(brow + d0);
        sb1[l] = *(const float4*)(brow + Ddim + d0);
    }

    // ---- C patch loads (stay in flight through staging + dot loop) ----
    // Thread covers C rows [8ty, 8ty+8), cols {4tx..4tx+3, 64+4tx..64+4tx+3}
    // within the tile. 16 lanes x 16B = dense 256B segments per instr.
    const size_t rowbase = (size_t)(by * 128 + 8 * ty) * NCOL
                         + (size_t)(bx * 128 + 4 * tx);
    float4 cv[8][2];
    #pragma unroll
    for (int rr = 0; rr < 8; ++rr) {
        const float* p = C + rowbase + (size_t)rr * NCOL;
        cv[rr][0] = *(const float4*)(p);
        cv[rr][1] = *(const float4*)(p + 64);
    }

    // ---- pair-sum into LDS (waits only on staging loads; cv still flying) --
    #pragma unroll
    for (int l = 0; l < 4; ++l) {
        const int d0 = dq * 16 + l * 4;
        // lanes vary j -> banks j%32, 2 lanes/bank (free)
        ACs[d0 + 0][j] = sa0[l].x + sa1[l].x;
        ACs[d0 + 1][j] = sa0[l].y + sa1[l].y;
        ACs[d0 + 2][j] = sa0[l].z + sa1[l].z;
        ACs[d0 + 3][j] = sa0[l].w + sa1[l].w;
        BCs[d0 + 0][j] = sb0[l].x + sb1[l].x;
        BCs[d0 + 1][j] = sb0[l].y + sb1[l].y;
        BCs[d0 + 2][j] = sb0[l].z + sb1[l].z;
        BCs[d0 + 3][j] = sb0[l].w + sb1[l].w;
    }
    __syncthreads();

    // ---- checksum dots: thread owns blocks bi in 4ty+{0..3},
    //      bj in {2tx, 2tx+1, 32+2tx, 33+2tx} ----
    float acc[4][4];
    #pragma unroll
    for (int a = 0; a < 4; ++a)
        #pragma unroll
        for (int b = 0; b < 4; ++b) acc[a][b] = 0.f;

    #pragma unroll 8
    for (int d = 0; d < 64; ++d) {
        float4 bc   = *(const float4*)&BCs[d][4 * ty];      // b128, bcast-free
        float2 ac01 = *(const float2*)&ACs[d][2 * tx];      // b64, conflict-free
        float2 ac23 = *(const float2*)&ACs[d][2 * tx + 32];
        const float bcv[4] = {bc.x, bc.y, bc.z, bc.w};
        const float acv[4] = {ac01.x, ac01.y, ac23.x, ac23.y};
        #pragma unroll
        for (int a = 0; a < 4; ++a)
            #pragma unroll
            for (int b = 0; b < 4; ++b)
                acc[a][b] += bcv[a] * acv[b];
    }

    // ---- block sums, compare, rare fix, store ----
    #pragma unroll
    for (int a = 0; a < 4; ++a) {
        float4 t0 = cv[2 * a][0], u0 = cv[2 * a + 1][0];
        float4 t1 = cv[2 * a][1], u1 = cv[2 * a + 1][1];
        float s0 = (t0.x + t0.y) + (u0.x + u0.y);
        float s1 = (t0.z + t0.w) + (u0.z + u0.w);
        float s2 = (t1.x + t1.y) + (u1.x + u1.y);
        float s3 = (t1.z + t1.w) + (u1.z + u1.w);
        bool f0 = fabsf(s0 - acc[a][0]) > ATOL + RTOL * fabsf(acc[a][0]);
        bool f1 = fabsf(s1 - acc[a][1]) > ATOL + RTOL * fabsf(acc[a][1]);
        bool f2 = fabsf(s2 - acc[a][2]) > ATOL + RTOL * fabsf(acc[a][2]);
        bool f3 = fabsf(s3 - acc[a][3]) > ATOL + RTOL * fabsf(acc[a][3]);
        if (f0 | f1 | f2 | f3) {   // ~670 of 16.7M blocks: fully divergent OK
            const int r0    = by * 128 + 8 * ty + 2 * a;
            const int cbase = bx * 128 + 4 * tx;
            if (f0) recompute2x2(A, B, r0, cbase,      t0.x, t0.y, u0.x, u0.y);
            if (f1) recompute2x2(A, B, r0, cbase + 2,  t0.z, t0.w, u0.z, u0.w);
            if (f2) recompute2x2(A, B, r0, cbase + 64, t1.x, t1.y, u1.x, u1.y);
            if (f3) recompute2x2(A, B, r0, cbase + 66, t1.z, t1.w, u1.z, u1.w);
        }
        float* q0 = out + rowbase + (size_t)(2 * a) * NCOL;
        float* q1 = out + rowbase + (size_t)(2 * a + 1) * NCOL;
        nt_store4(q0,      t0);
        nt_store4(q0 + 64, t1);
        nt_store4(q1,      u0);
        nt_store4(q1 + 64, u1);
    }
}

extern "C" void kernel_launch(void* const* d_in, const int* in_sizes, int n_in,
                              void* d_out, int out_size, void* d_ws, size_t ws_size,
                              hipStream_t stream) {
    const float* A = (const float*)d_in[0];   // (8192, 64)
    const float* B = (const float*)d_in[1];   // (8192, 64)
    const float* C = (const float*)d_in[2];   // (8192, 8192) faulty
    float* out = (float*)d_out;               // (8192, 8192)
    dim3 grid(NCOL / 128, NCOL / 128);        // 64 x 64 tiles
    correct_kernel<<<grid, 256, 0, stream>>>(A, B, C, out);
}

// Round 4
// 110.331 us; speedup vs baseline: 1.2866x; 1.0237x over previous
//
#include <hip/hip_runtime.h>

// Correction_Module_dense_checksum: ABFT 2x2 block checksum verify + correct.
// A: (8192, 64) f32, B: (8192, 64) f32, C_faulty: (8192, 8192) f32 -> out f32.
// check[i][j] = (B[2i]+B[2i+1]) . (A[2j]+A[2j+1]); actual = 2x2 block sum of C.
// Flag iff |actual - check| > ATOL + RTOL*|check|; flagged 2x2 blocks are
// recomputed as B[r] . A[c]. Fault margin ~100 vs tol ~1e-3 -> mask is
// reproduction-robust under any f32 summation order.
//
// R4: 64x64 tile / 256 threads. R3 showed the compiler pins VGPR=64 and
// serializes loads when per-thread load data exceeds the budget (occ 35%,
// 3.6 TB/s). New shape: 8 staging float4 + 4 cv float4 = 48 regs of loads ->
// all in flight under 64 VGPR; LDS 16 KB -> 8 blocks/CU (wave-slot cap).

constexpr int   Ddim = 64;
constexpr int   NCOL = 8192;
constexpr float ATOL = 1e-3f;
constexpr float RTOL = 1e-4f;

typedef float vfloat4 __attribute__((ext_vector_type(4)));

__device__ __forceinline__ void nt_store4(float* p, float4 v) {
    vfloat4 w = {v.x, v.y, v.z, v.w};
    __builtin_nontemporal_store(w, (vfloat4*)p);
}

__device__ __forceinline__ void recompute2x2(const float* __restrict__ A,
                                             const float* __restrict__ B,
                                             int r0, int c0,
                                             float& e00, float& e01,
                                             float& e10, float& e11)
{
    const float* b0 = B + (size_t)r0 * Ddim;
    const float* b1 = b0 + Ddim;
    const float* a0 = A + (size_t)c0 * Ddim;
    const float* a1 = a0 + Ddim;
    float d00 = 0.f, d01 = 0.f, d10 = 0.f, d11 = 0.f;
    for (int d = 0; d < Ddim; ++d) {
        float bb0 = b0[d], bb1 = b1[d], aa0 = a0[d], aa1 = a1[d];
        d00 += bb0 * aa0;
        d01 += bb0 * aa1;
        d10 += bb1 * aa0;
        d11 += bb1 * aa1;
    }
    e00 = d00; e01 = d01; e10 = d10; e11 = d11;
}

__global__ __launch_bounds__(256, 8)
void correct_kernel(const float* __restrict__ A, const float* __restrict__ B,
                    const float* __restrict__ C, float* __restrict__ out)
{
    // [d][j] layout: dot-loop lane reads vary j -> spread across banks;
    // same-address reads broadcast. 8 KB each.
    __shared__ float ACs[64][32];   // checksum of A row-pairs for 32 j-blocks
    __shared__ float BCs[64][32];   // checksum of B row-pairs for 32 i-blocks

    const int t   = threadIdx.x;
    const int bx  = blockIdx.x;     // 64-col tile
    const int by  = blockIdx.y;     // 64-row tile
    const int tj2 = t & 15;         // thread's j-block pair (cols 4*tj2..+3)
    const int ti2 = t >> 4;         // thread's i-block pair (rows 4*ti2..+3)

    // ---- staging loads FIRST (they gate the barrier): 8 float4 ----
    const int js = t & 31;          // staged block index within tile
    const int d0 = (t >> 5) * 8;    // this thread's d-chunk
    const float* arow = A + (size_t)(bx * 32 + js) * 2 * Ddim;
    const float* brow = B + (size_t)(by * 32 + js) * 2 * Ddim;
    float4 sa[4], sb[4];
    sa[0] = *(const float4*)(arow + d0);
    sa[1] = *(const float4*)(arow + d0 + 4);
    sa[2] = *(const float4*)(arow + Ddim + d0);
    sa[3] = *(const float4*)(arow + Ddim + d0 + 4);
    sb[0] = *(const float4*)(brow + d0);
    sb[1] = *(const float4*)(brow + d0 + 4);
    sb[2] = *(const float4*)(brow + Ddim + d0);
    sb[3] = *(const float4*)(brow + Ddim + d0 + 4);

    // ---- C patch loads: 4 float4, stay in flight through the dot loop ----
    // 16 lanes x 16B = dense 256B segments per row.
    const size_t rowbase = (size_t)(by * 64 + 4 * ti2) * NCOL
                         + (size_t)(bx * 64 + 4 * tj2);
    float4 cv[4];
    #pragma unroll
    for (int r = 0; r < 4; ++r)
        cv[r] = *(const float4*)(C + rowbase + (size_t)r * NCOL);

    // ---- pair-sum into LDS (waits only on staging; cv still flying) ----
    // banks = js%32, 2 lanes/bank (free).
    #pragma unroll
    for (int k = 0; k < 4; ++k) {
        ACs[d0 + k    ][js] = ((const float*)&sa[0])[k] + ((const float*)&sa[2])[k];
        ACs[d0 + k + 4][js] = ((const float*)&sa[1])[k] + ((const float*)&sa[3])[k];
        BCs[d0 + k    ][js] = ((const float*)&sb[0])[k] + ((const float*)&sb[2])[k];
        BCs[d0 + k + 4][js] = ((const float*)&sb[1])[k] + ((const float*)&sb[3])[k];
    }
    __syncthreads();

    // ---- checksum dots: thread owns 2x2 blocks (2ti2+{0,1}) x (2tj2+{0,1}) --
    float a00 = 0.f, a01 = 0.f, a10 = 0.f, a11 = 0.f;
    #pragma unroll 16
    for (int d = 0; d < 64; ++d) {
        float2 bc = *(const float2*)&BCs[d][2 * ti2];   // 4 addrs, broadcast
        float2 ac = *(const float2*)&ACs[d][2 * tj2];   // 32 banks, 2-way free
        a00 += bc.x * ac.x;
        a01 += bc.x * ac.y;
        a10 += bc.y * ac.x;
        a11 += bc.y * ac.y;
    }

    // ---- block sums, compare, rare fix, store ----
    float s00 = (cv[0].x + cv[0].y) + (cv[1].x + cv[1].y);
    float s01 = (cv[0].z + cv[0].w) + (cv[1].z + cv[1].w);
    float s10 = (cv[2].x + cv[2].y) + (cv[3].x + cv[3].y);
    float s11 = (cv[2].z + cv[2].w) + (cv[3].z + cv[3].w);
    bool f00 = fabsf(s00 - a00) > ATOL + RTOL * fabsf(a00);
    bool f01 = fabsf(s01 - a01) > ATOL + RTOL * fabsf(a01);
    bool f10 = fabsf(s10 - a10) > ATOL + RTOL * fabsf(a10);
    bool f11 = fabsf(s11 - a11) > ATOL + RTOL * fabsf(a11);
    if (f00 | f01 | f10 | f11) {    // ~670 of 16.7M blocks: divergence is fine
        const int r0 = by * 64 + 4 * ti2;
        const int c0 = bx * 64 + 4 * tj2;
        if (f00) recompute2x2(A, B, r0,     c0,     cv[0].x, cv[0].y, cv[1].x, cv[1].y);
        if (f01) recompute2x2(A, B, r0,     c0 + 2, cv[0].z, cv[0].w, cv[1].z, cv[1].w);
        if (f10) recompute2x2(A, B, r0 + 2, c0,     cv[2].x, cv[2].y, cv[3].x, cv[3].y);
        if (f11) recompute2x2(A, B, r0 + 2, c0 + 2, cv[2].z, cv[2].w, cv[3].z, cv[3].w);
    }
    #pragma unroll
    for (int r = 0; r < 4; ++r)
        nt_store4(out + rowbase + (size_t)r * NCOL, cv[r]);
}

extern "C" void kernel_launch(void* const* d_in, const int* in_sizes, int n_in,
                              void* d_out, int out_size, void* d_ws, size_t ws_size,
                              hipStream_t stream) {
    const float* A = (const float*)d_in[0];   // (8192, 64)
    const float* B = (const float*)d_in[1];   // (8192, 64)
    const float* C = (const float*)d_in[2];   // (8192, 8192) faulty
    float* out = (float*)d_out;               // (8192, 8192)
    dim3 grid(NCOL / 64, NCOL / 64);          // 128 x 128 tiles
    correct_kernel<<<grid, 256, 0, stream>>>(A, B, C, out);
}

// Round 5
// 110.230 us; speedup vs baseline: 1.2877x; 1.0009x over previous
//
#include <hip/hip_runtime.h>

// Correction_Module_dense_checksum: ABFT 2x2 block checksum verify + correct.
// A: (8192, 64) f32, B: (8192, 64) f32, C_faulty: (8192, 8192) f32 -> out f32.
// check[i][j] = (B[2i]+B[2i+1]) . (A[2j]+A[2j+1]); actual = 2x2 block sum of C.
// Flag iff |actual - check| > ATOL + RTOL*|check|; flagged 2x2 blocks are
// recomputed as B[r] . A[c]. Fault margin ~100 vs tol ~1e-3 -> mask is
// reproduction-robust under any f32 summation order.
//
// R5: DRAM-burst-length theory. R4 falsified MLP/occupancy (occ 35->67%, dur
// 113->110us). Invariant: 64x64 tiles read/write C as 256B chunks at 32KB
// stride -> short scattered DRAM bursts. New tile 32x256: every wave
// load/store = 1KB contiguous; adjacent blockIdx.x blocks extend the same
// rows -> long merged streams. AC staging redundancy (537MB aggregate) is
// L2/L3-resident A, hidden under the HBM stream.

constexpr int   Ddim = 64;
constexpr int   NCOL = 8192;
constexpr int   ROWS = 32;    // tile rows per block
constexpr int   COLS = 256;   // tile cols per block
constexpr float ATOL = 1e-3f;
constexpr float RTOL = 1e-4f;

typedef float vfloat4 __attribute__((ext_vector_type(4)));

__device__ __forceinline__ void nt_store4(float* p, float4 v) {
    vfloat4 w = {v.x, v.y, v.z, v.w};
    __builtin_nontemporal_store(w, (vfloat4*)p);
}

__device__ __forceinline__ void recompute2x2(const float* __restrict__ A,
                                             const float* __restrict__ B,
                                             int r0, int c0,
                                             float& e00, float& e01,
                                             float& e10, float& e11)
{
    const float* b0 = B + (size_t)r0 * Ddim;
    const float* b1 = b0 + Ddim;
    const float* a0 = A + (size_t)c0 * Ddim;
    const float* a1 = a0 + Ddim;
    float d00 = 0.f, d01 = 0.f, d10 = 0.f, d11 = 0.f;
    for (int d = 0; d < Ddim; ++d) {
        float bb0 = b0[d], bb1 = b1[d], aa0 = a0[d], aa1 = a1[d];
        d00 += bb0 * aa0;
        d01 += bb0 * aa1;
        d10 += bb1 * aa0;
        d11 += bb1 * aa1;
    }
    e00 = d00; e01 = d01; e10 = d10; e11 = d11;
}

__global__ __launch_bounds__(256, 4)
void correct_kernel(const float* __restrict__ A, const float* __restrict__ B,
                    const float* __restrict__ C, float* __restrict__ out)
{
    // [d][j] layout. AC dot-read is 512B/wave = inherent 4 LDS cycles
    // (BW-optimal); BC dot-read is wave-uniform broadcast.
    __shared__ float ACs[64][128];   // pair-summed A for 128 j-blocks, 32 KiB
    __shared__ float BCs[64][16];    // pair-summed B for 16 i-blocks,  4 KiB

    const int t  = threadIdx.x;
    const int bx = blockIdx.x;       // 256-col tile
    const int by = blockIdx.y;       // 32-row strip
    const int w  = t >> 6;           // wave 0..3
    const int l  = t & 63;           // lane

    // ---- staging loads first (they gate the barrier) ----
    // AC: thread covers j-block jj, d-half q (32 d's): 16 float4 from L2.
    const int jj = t & 127;
    const int q  = t >> 7;
    const float* arow = A + (size_t)(bx * 128 + jj) * 2 * Ddim + q * 32;
    float4 sa0[8], sa1[8];
    #pragma unroll
    for (int i = 0; i < 8; ++i) {
        sa0[i] = *(const float4*)(arow + 4 * i);
        sa1[i] = *(const float4*)(arow + Ddim + 4 * i);
    }
    // BC: thread covers i-block ib, d-chunk dh (4 d's): 2 float4.
    const int ib = t & 15;
    const int dh = t >> 4;
    const float* brow = B + (size_t)(by * ROWS + 2 * ib) * Ddim + dh * 4;
    float4 sb0 = *(const float4*)(brow);
    float4 sb1 = *(const float4*)(brow + Ddim);

    // ---- C loads: wave w covers rows 8w..8w+7, lane l cols 4l..4l+3 ----
    // One instr = 64 lanes x 16B = 1 KB contiguous (full tile row).
    const size_t rowbase = (size_t)(by * ROWS + 8 * w) * NCOL
                         + (size_t)(bx * COLS + 4 * l);
    float4 cv[8];
    #pragma unroll
    for (int rr = 0; rr < 8; ++rr)
        cv[rr] = *(const float4*)(C + rowbase + (size_t)rr * NCOL);

    // ---- pair-sum into LDS (waits staging only; cv stays in flight) ----
    #pragma unroll
    for (int i = 0; i < 8; ++i) {
        const int d0 = q * 32 + 4 * i;
        #pragma unroll
        for (int k = 0; k < 4; ++k)   // banks = jj%32, 2 lanes/bank: free
            ACs[d0 + k][jj] = ((const float*)&sa0[i])[k] + ((const float*)&sa1[i])[k];
    }
    #pragma unroll
    for (int k = 0; k < 4; ++k)
        BCs[dh * 4 + k][ib] = ((const float*)&sb0)[k] + ((const float*)&sb1)[k];
    __syncthreads();

    // ---- checksum dots: thread owns i-blocks 4w+a (a=0..3), j-blocks 2l+b --
    float acc[4][2];
    #pragma unroll
    for (int a = 0; a < 4; ++a) { acc[a][0] = 0.f; acc[a][1] = 0.f; }

    #pragma unroll 16
    for (int d = 0; d < 64; ++d) {
        float4 bc = *(const float4*)&BCs[d][4 * w];   // wave-uniform: bcast
        float2 ac = *(const float2*)&ACs[d][2 * l];   // 512B/wave: 4cy, full BW
        const float bcv[4] = {bc.x, bc.y, bc.z, bc.w};
        #pragma unroll
        for (int a = 0; a < 4; ++a) {
            acc[a][0] += bcv[a] * ac.x;
            acc[a][1] += bcv[a] * ac.y;
        }
    }

    // ---- block sums, compare, rare fix, store ----
    #pragma unroll
    for (int a = 0; a < 4; ++a) {
        float4 c0 = cv[2 * a], c1 = cv[2 * a + 1];
        float s0 = (c0.x + c0.y) + (c1.x + c1.y);
        float s1 = (c0.z + c0.w) + (c1.z + c1.w);
        bool f0 = fabsf(s0 - acc[a][0]) > ATOL + RTOL * fabsf(acc[a][0]);
        bool f1 = fabsf(s1 - acc[a][1]) > ATOL + RTOL * fabsf(acc[a][1]);
        if (f0 | f1) {               // ~670 of 16.7M blocks: divergence fine
            const int r0 = by * ROWS + 8 * w + 2 * a;
            const int c0i = bx * COLS + 4 * l;
            if (f0) recompute2x2(A, B, r0, c0i,     c0.x, c0.y, c1.x, c1.y);
            if (f1) recompute2x2(A, B, r0, c0i + 2, c0.z, c0.w, c1.z, c1.w);
        }
        nt_store4(out + rowbase + (size_t)(2 * a) * NCOL,     c0);
        nt_store4(out + rowbase + (size_t)(2 * a + 1) * NCOL, c1);
    }
}

extern "C" void kernel_launch(void* const* d_in, const int* in_sizes, int n_in,
                              void* d_out, int out_size, void* d_ws, size_t ws_size,
                              hipStream_t stream) {
    const float* A = (const float*)d_in[0];   // (8192, 64)
    const float* B = (const float*)d_in[1];   // (8192, 64)
    const float* C = (const float*)d_in[2];   // (8192, 8192) faulty
    float* out = (float*)d_out;               // (8192, 8192)
    dim3 grid(NCOL / COLS, NCOL / ROWS);      // 32 x 256; x-fastest = adjacent
    correct_kernel<<<grid, 256, 0, stream>>>(A, B, C, out);   // col segments
}